// Round 1
// baseline (776.543 us; speedup 1.0000x reference)
//
#include <hip/hip_runtime.h>
#include <math.h>

#define NN 25000
#define EE 400000
#define FF 128
#define DD 16
#define HH 64
#define HIDC 128
#define OUTC 32
#define GG 64

__device__ __forceinline__ float silu_f(float v) {
    return v / (1.f + __expf(-v));
}

// ---------------- K1: P1 = X @ W[0:128,:], P2 = X @ W[128:256,:] ----------------
// 8 nodes per wave, x staged transposed in LDS (stride 12 floats: 16B-aligned rows).
__global__ __launch_bounds__(256) void k_precompute(
    const float* __restrict__ X, const float* __restrict__ W,
    float* __restrict__ P1, float* __restrict__ P2) {
  __shared__ __align__(16) float xT[4][128 * 12];
  const int w = threadIdx.x >> 6, lane = threadIdx.x & 63;
  float* xt = xT[w];
  const int nb = (blockIdx.x * 4 + w) * 8;
#pragma unroll
  for (int e = 0; e < 8; ++e) {
    const int n = nb + e;
    const bool v = n < NN;
    xt[lane * 12 + e]        = v ? X[n * FF + lane] : 0.f;
    xt[(lane + 64) * 12 + e] = v ? X[n * FF + 64 + lane] : 0.f;
  }
  __syncthreads();
  float a1[8], a2[8];
#pragma unroll
  for (int e = 0; e < 8; ++e) { a1[e] = 0.f; a2[e] = 0.f; }
#pragma unroll 4
  for (int k = 0; k < 128; ++k) {
    const float wa = W[k * 64 + lane];
    const float wb = W[(128 + k) * 64 + lane];
    float xk[8];
    *(float4*)&xk[0] = *(const float4*)&xt[k * 12];
    *(float4*)&xk[4] = *(const float4*)&xt[k * 12 + 4];
#pragma unroll
    for (int e = 0; e < 8; ++e) {
      a1[e] = fmaf(xk[e], wa, a1[e]);
      a2[e] = fmaf(xk[e], wb, a2[e]);
    }
  }
#pragma unroll
  for (int e = 0; e < 8; ++e) {
    const int n = nb + e;
    if (n < NN) {
      P1[n * 64 + lane] = a1[e];
      P2[n * 64 + lane] = a2[e];
    }
  }
}

// ---------------- K2: per-edge MLP + scatter-add aggregation ----------------
// 4 edges per wave; edge_w/W3 staged in LDS; h round-trips via per-wave LDS.
template <bool COORD>
__global__ __launch_bounds__(256) void k_edge(
    const float* __restrict__ P1, const float* __restrict__ P2,
    const float* __restrict__ pos, const float* __restrict__ eattr,
    const int* __restrict__ ei, const float* __restrict__ mlp_w,
    const float* __restrict__ edge_w, const float* __restrict__ edge_b,
    const float* __restrict__ coord_w, const float* __restrict__ coord_b,
    float* __restrict__ e_agg, float* __restrict__ cu, float* __restrict__ deg) {
  __shared__ __align__(16) float s_ew[64 * 64];
  __shared__ __align__(16) float s_w3[16 * 64];
  __shared__ float s_w4[64];
  __shared__ float s_cw[64];
  __shared__ float s_eb[64];
  __shared__ __align__(16) float s_eaT[4][64];
  __shared__ __align__(16) float s_hT[4][256];
  const int tid = threadIdx.x, w = tid >> 6, lane = tid & 63;
  for (int i = tid; i < 64 * 64; i += 256) s_ew[i] = edge_w[i];
  for (int i = tid; i < 16 * 64; i += 256) s_w3[i] = mlp_w[256 * 64 + i];
  if (tid < 64) {
    s_w4[tid] = mlp_w[272 * 64 + tid];
    s_cw[tid] = coord_w[tid];
    s_eb[tid] = edge_b[tid];
  }
  const float cb = COORD ? coord_b[0] : 0.f;
  __syncthreads();

  const int wave_id = blockIdx.x * 4 + w;
  const int ee = lane >> 4, kk = lane & 15;
  for (int grp = 0; grp < 10; ++grp) {
    const int eb = (wave_id * 10 + grp) * 4;
    int srcs[4], dsts[4];
#pragma unroll
    for (int e = 0; e < 4; ++e) { srcs[e] = ei[eb + e]; dsts[e] = ei[EE + eb + e]; }
    // stage edge_attr transposed: eaT[k][e], one element per lane
    s_eaT[w][kk * 4 + ee] = eattr[(eb + ee) * DD + kk];
    float dx[4], dy[4], dz[4], rad[4];
#pragma unroll
    for (int e = 0; e < 4; ++e) {
      const float ax = pos[dsts[e] * 3 + 0], ay = pos[dsts[e] * 3 + 1], az = pos[dsts[e] * 3 + 2];
      const float bx = pos[srcs[e] * 3 + 0], by = pos[srcs[e] * 3 + 1], bz = pos[srcs[e] * 3 + 2];
      dx[e] = ax - bx; dy[e] = ay - by; dz[e] = az - bz;
      rad[e] = dx[e] * dx[e] + dy[e] * dy[e] + dz[e] * dz[e];
    }
    float acc[4];
#pragma unroll
    for (int e = 0; e < 4; ++e)
      acc[e] = P1[dsts[e] * 64 + lane] + P2[srcs[e] * 64 + lane] + rad[e] * s_w4[lane];
#pragma unroll
    for (int k = 0; k < 16; ++k) {
      const float4 av = *(const float4*)&s_eaT[w][k * 4];
      const float wv = s_w3[k * 64 + lane];
      acc[0] = fmaf(av.x, wv, acc[0]);
      acc[1] = fmaf(av.y, wv, acc[1]);
      acc[2] = fmaf(av.z, wv, acc[2]);
      acc[3] = fmaf(av.w, wv, acc[3]);
    }
#pragma unroll
    for (int e = 0; e < 4; ++e) acc[e] = silu_f(acc[e]);
    *(float4*)&s_hT[w][lane * 4] = make_float4(acc[0], acc[1], acc[2], acc[3]);
    float o[4];
#pragma unroll
    for (int e = 0; e < 4; ++e) o[e] = s_eb[lane];
#pragma unroll 8
    for (int k = 0; k < 64; ++k) {
      const float4 hv = *(const float4*)&s_hT[w][k * 4];
      const float wv = s_ew[k * 64 + lane];
      o[0] = fmaf(hv.x, wv, o[0]);
      o[1] = fmaf(hv.y, wv, o[1]);
      o[2] = fmaf(hv.z, wv, o[2]);
      o[3] = fmaf(hv.w, wv, o[3]);
    }
#pragma unroll
    for (int e = 0; e < 4; ++e) o[e] = silu_f(o[e]);
#pragma unroll
    for (int e = 0; e < 4; ++e)
      atomicAdd(&e_agg[dsts[e] * 64 + lane], o[e]);
    if (COORD) {
      float vv[4];
#pragma unroll
      for (int e = 0; e < 4; ++e) vv[e] = o[e] * s_cw[lane];
#pragma unroll
      for (int off = 32; off > 0; off >>= 1) {
#pragma unroll
        for (int e = 0; e < 4; ++e) vv[e] += __shfl_xor(vv[e], off, 64);
      }
#pragma unroll
      for (int e = 0; e < 4; ++e) {
        const float s = silu_f(vv[e] + cb);
        if (lane < 3) {
          const float dc = (lane == 0) ? dx[e] : ((lane == 1) ? dy[e] : dz[e]);
          atomicAdd(&cu[dsts[e] * 3 + lane], dc * s);
        }
        if (lane == 3) atomicAdd(&deg[dsts[e]], 1.f);
      }
    }
  }
}

// ---------------- K3: node MLP (+ pos update on layer 0) ----------------
template <bool L0>
__global__ __launch_bounds__(256) void k_node(
    const float* __restrict__ x_in, const float* __restrict__ e_agg,
    const float* __restrict__ nw1, const float* __restrict__ nb1,
    const float* __restrict__ nw2, const float* __restrict__ nb2,
    const float* __restrict__ pos_in, const float* __restrict__ cu,
    const float* __restrict__ deg,
    float* __restrict__ x_out, float* __restrict__ pos_out) {
  __shared__ __align__(16) float xT[4][192 * 12];
  const int w = threadIdx.x >> 6, lane = threadIdx.x & 63;
  float* xt = xT[w];
  const int nb = (blockIdx.x * 4 + w) * 8;
#pragma unroll
  for (int e = 0; e < 8; ++e) {
    const int n = nb + e;
    const bool v = n < NN;
    xt[lane * 12 + e]         = v ? x_in[n * HIDC + lane] : 0.f;
    xt[(64 + lane) * 12 + e]  = v ? x_in[n * HIDC + 64 + lane] : 0.f;
    xt[(128 + lane) * 12 + e] = v ? e_agg[n * 64 + lane] : 0.f;
  }
  __syncthreads();
  float a[8];
#pragma unroll
  for (int e = 0; e < 8; ++e) a[e] = nb1[lane];
#pragma unroll 2
  for (int k = 0; k < 192; ++k) {
    const float wv = nw1[k * 64 + lane];
    float xk[8];
    *(float4*)&xk[0] = *(const float4*)&xt[k * 12];
    *(float4*)&xk[4] = *(const float4*)&xt[k * 12 + 4];
#pragma unroll
    for (int e = 0; e < 8; ++e) a[e] = fmaf(xk[e], wv, a[e]);
  }
#pragma unroll
  for (int e = 0; e < 8; ++e) a[e] = silu_f(a[e]);
  // overwrite rows 0..63 with silu(h1), transposed (same-wave WAR: DS in-order)
  *(float4*)&xt[lane * 12]     = make_float4(a[0], a[1], a[2], a[3]);
  *(float4*)&xt[lane * 12 + 4] = make_float4(a[4], a[5], a[6], a[7]);
  float olo[8], ohi[8];
#pragma unroll
  for (int e = 0; e < 8; ++e) { olo[e] = nb2[lane]; ohi[e] = nb2[64 + lane]; }
#pragma unroll 2
  for (int k = 0; k < 64; ++k) {
    const float wl = nw2[k * HIDC + lane];
    const float wh = nw2[k * HIDC + 64 + lane];
    float hk[8];
    *(float4*)&hk[0] = *(const float4*)&xt[k * 12];
    *(float4*)&hk[4] = *(const float4*)&xt[k * 12 + 4];
#pragma unroll
    for (int e = 0; e < 8; ++e) {
      olo[e] = fmaf(hk[e], wl, olo[e]);
      ohi[e] = fmaf(hk[e], wh, ohi[e]);
    }
  }
#pragma unroll
  for (int e = 0; e < 8; ++e) {
    const int n = nb + e;
    if (n < NN) {
      x_out[n * HIDC + lane]      = olo[e];
      x_out[n * HIDC + 64 + lane] = ohi[e];
    }
  }
  if (L0) {
#pragma unroll
    for (int e = 0; e < 8; ++e) {
      const int n = nb + e;
      if (n < NN && lane < 3) {
        const float dg = fmaxf(deg[n], 1.f);
        pos_out[n * 3 + lane] = pos_in[n * 3 + lane] + cu[n * 3 + lane] / dg;
      }
    }
  }
}

// ---------------- K4: graph mean-pool partials (batch is sorted) ----------------
__global__ __launch_bounds__(128) void k_pool(
    const float* __restrict__ x, const int* __restrict__ batch,
    float* __restrict__ g_sum, float* __restrict__ g_cnt) {
  const int j = threadIdx.x;  // 0..127
  const int n0 = blockIdx.x * 256;
  const int n1 = min(n0 + 256, NN);
  int cur = batch[n0];
  float acc = 0.f, cnt = 0.f;
  for (int n = n0; n < n1; ++n) {
    const int b = batch[n];  // uniform across threads
    if (b != cur) {
      atomicAdd(&g_sum[cur * HIDC + j], acc);
      if (j == 0) atomicAdd(&g_cnt[cur], cnt);
      acc = 0.f; cnt = 0.f; cur = b;
    }
    acc += x[n * HIDC + j];
    cnt += 1.f;
  }
  atomicAdd(&g_sum[cur * HIDC + j], acc);
  if (j == 0) atomicAdd(&g_cnt[cur], cnt);
}

// ---------------- K5: relu(mean) -> relu(@w1+b1) -> @w2+b2 ----------------
__global__ __launch_bounds__(128) void k_final(
    const float* __restrict__ g_sum, const float* __restrict__ g_cnt,
    const float* __restrict__ w1, const float* __restrict__ b1,
    const float* __restrict__ w2, const float* __restrict__ b2,
    float* __restrict__ out) {
  __shared__ float sg[128];
  __shared__ float sh[128];
  const int g = blockIdx.x, j = threadIdx.x;
  const float c = fmaxf(g_cnt[g], 1.f);
  sg[j] = fmaxf(g_sum[g * HIDC + j] / c, 0.f);
  __syncthreads();
  float a = b1[j];
  for (int k = 0; k < 128; ++k) a += sg[k] * w1[k * 128 + j];
  sh[j] = fmaxf(a, 0.f);
  __syncthreads();
  if (j < OUTC) {
    float o = b2[j];
    for (int k = 0; k < 128; ++k) o += sh[k] * w2[k * OUTC + j];
    out[g * OUTC + j] = o;
  }
}

extern "C" void kernel_launch(void* const* d_in, const int* in_sizes, int n_in,
                              void* d_out, int out_size, void* d_ws, size_t ws_size,
                              hipStream_t stream) {
  const float* x     = (const float*)d_in[0];
  const float* pos   = (const float*)d_in[1];
  const float* eattr = (const float*)d_in[2];
  const int*   ei    = (const int*)d_in[3];
  const int*   batch = (const int*)d_in[4];
  const float* mlp_w[2]   = {(const float*)d_in[5],  (const float*)d_in[14]};
  const float* edge_w[2]  = {(const float*)d_in[6],  (const float*)d_in[15]};
  const float* edge_b[2]  = {(const float*)d_in[7],  (const float*)d_in[16]};
  const float* coord_w[2] = {(const float*)d_in[8],  (const float*)d_in[17]};
  const float* coord_b[2] = {(const float*)d_in[9],  (const float*)d_in[18]};
  const float* nw1[2]     = {(const float*)d_in[10], (const float*)d_in[19]};
  const float* nb1[2]     = {(const float*)d_in[11], (const float*)d_in[20]};
  const float* nw2[2]     = {(const float*)d_in[12], (const float*)d_in[21]};
  const float* nb2[2]     = {(const float*)d_in[13], (const float*)d_in[22]};
  const float* ow1 = (const float*)d_in[23];
  const float* ob1 = (const float*)d_in[24];
  const float* ow2 = (const float*)d_in[25];
  const float* ob2 = (const float*)d_in[26];
  float* out = (float*)d_out;

  char* p = (char*)d_ws;
  auto alloc = [&](size_t bytes) {
    float* r = (float*)p;
    p += (bytes + 255) & ~(size_t)255;
    return r;
  };
  float* P1    = alloc((size_t)NN * 64 * 4);
  float* P2    = alloc((size_t)NN * 64 * 4);
  float* e_agg = alloc((size_t)NN * 64 * 4);
  float* cu    = alloc((size_t)NN * 3 * 4);
  float* deg   = alloc((size_t)NN * 4);
  float* x1    = alloc((size_t)NN * HIDC * 4);
  float* pos1  = alloc((size_t)NN * 3 * 4);
  float* g_sum = alloc((size_t)GG * HIDC * 4);
  float* g_cnt = alloc((size_t)GG * 4);
  float* x2    = P1;  // alias: P1+P2 (contiguous 12.8 MB) dead after layer-1 k_edge

  const int nodeBlocks = (NN + 31) / 32;

  hipMemsetAsync(e_agg, 0, (size_t)NN * 64 * 4, stream);
  hipMemsetAsync(cu,    0, (size_t)NN * 3 * 4, stream);
  hipMemsetAsync(deg,   0, (size_t)NN * 4, stream);
  hipMemsetAsync(g_sum, 0, (size_t)GG * HIDC * 4, stream);
  hipMemsetAsync(g_cnt, 0, (size_t)GG * 4, stream);

  // ---- layer 0 ----
  k_precompute<<<nodeBlocks, 256, 0, stream>>>(x, mlp_w[0], P1, P2);
  k_edge<true><<<2500, 256, 0, stream>>>(P1, P2, pos, eattr, ei, mlp_w[0],
      edge_w[0], edge_b[0], coord_w[0], coord_b[0], e_agg, cu, deg);
  k_node<true><<<nodeBlocks, 256, 0, stream>>>(x, e_agg, nw1[0], nb1[0],
      nw2[0], nb2[0], pos, cu, deg, x1, pos1);

  // ---- layer 1 (output pos unused -> skip coord path) ----
  hipMemsetAsync(e_agg, 0, (size_t)NN * 64 * 4, stream);
  k_precompute<<<nodeBlocks, 256, 0, stream>>>(x1, mlp_w[1], P1, P2);
  k_edge<false><<<2500, 256, 0, stream>>>(P1, P2, pos1, eattr, ei, mlp_w[1],
      edge_w[1], edge_b[1], coord_w[1], coord_b[1], e_agg, cu, deg);
  k_node<false><<<nodeBlocks, 256, 0, stream>>>(x1, e_agg, nw1[1], nb1[1],
      nw2[1], nb2[1], pos1, cu, deg, x2, pos1);

  // ---- pooling + head ----
  k_pool<<<(NN + 255) / 256, 128, 0, stream>>>(x2, batch, g_sum, g_cnt);
  k_final<<<GG, 128, 0, stream>>>(g_sum, g_cnt, ow1, ob1, ow2, ob2, out);
}

// Round 2
// 730.852 us; speedup vs baseline: 1.0625x; 1.0625x over previous
//
#include <hip/hip_runtime.h>
#include <math.h>

#define NN 25000
#define EE 400000
#define FF 128
#define DD 16
#define HH 64
#define HIDC 128
#define OUTC 32
#define GG 64

__device__ __forceinline__ float silu_f(float v) {
    return v / (1.f + __expf(-v));
}

// ---------------- K1: P1 = X @ W[0:128,:], P2 = X @ W[128:256,:] ----------------
__global__ __launch_bounds__(256) void k_precompute(
    const float* __restrict__ X, const float* __restrict__ W,
    float* __restrict__ P1, float* __restrict__ P2) {
  __shared__ __align__(16) float xT[4][128 * 12];
  const int w = threadIdx.x >> 6, lane = threadIdx.x & 63;
  float* xt = xT[w];
  const int nb = (blockIdx.x * 4 + w) * 8;
#pragma unroll
  for (int e = 0; e < 8; ++e) {
    const int n = nb + e;
    const bool v = n < NN;
    xt[lane * 12 + e]        = v ? X[n * FF + lane] : 0.f;
    xt[(lane + 64) * 12 + e] = v ? X[n * FF + 64 + lane] : 0.f;
  }
  __syncthreads();
  float a1[8], a2[8];
#pragma unroll
  for (int e = 0; e < 8; ++e) { a1[e] = 0.f; a2[e] = 0.f; }
#pragma unroll 4
  for (int k = 0; k < 128; ++k) {
    const float wa = W[k * 64 + lane];
    const float wb = W[(128 + k) * 64 + lane];
    float xk[8];
    *(float4*)&xk[0] = *(const float4*)&xt[k * 12];
    *(float4*)&xk[4] = *(const float4*)&xt[k * 12 + 4];
#pragma unroll
    for (int e = 0; e < 8; ++e) {
      a1[e] = fmaf(xk[e], wa, a1[e]);
      a2[e] = fmaf(xk[e], wb, a2[e]);
    }
  }
#pragma unroll
  for (int e = 0; e < 8; ++e) {
    const int n = nb + e;
    if (n < NN) {
      P1[n * 64 + lane] = a1[e];
      P2[n * 64 + lane] = a2[e];
    }
  }
}

// ---------------- K2: per-edge MLP + scatter-add, software-pipelined ----------------
// 8 edges per wave per group, 10 groups. 1250 blocks x 4 waves x 80 edges = 400000.
// All per-group global loads for group g+1 are issued before computing group g.
template <bool COORD>
__global__ __launch_bounds__(256, 4) void k_edge(
    const float* __restrict__ P1, const float* __restrict__ P2,
    const float* __restrict__ pos, const float* __restrict__ eattr,
    const int* __restrict__ ei, const float* __restrict__ mlp_w,
    const float* __restrict__ edge_w, const float* __restrict__ edge_b,
    const float* __restrict__ coord_w, const float* __restrict__ coord_b,
    float* __restrict__ e_agg, float* __restrict__ cu, float* __restrict__ deg) {
  __shared__ __align__(16) float s_ew[64 * 64];
  __shared__ __align__(16) float s_w3[16 * 64];
  __shared__ float s_w4[64];
  __shared__ float s_cw[64];
  __shared__ float s_eb[64];
  __shared__ int s_src[320];
  __shared__ int s_dst[320];
  __shared__ __align__(16) float s_eaT[4][2][128];   // [k][e], k-stride 8
  __shared__ float s_diff[4][2][24];                 // [e][c]
  __shared__ __align__(16) float s_hT[4][512];       // [lane][e], lane-stride 8
  const int tid = threadIdx.x, w = tid >> 6, lane = tid & 63;
  for (int i = tid; i < 64 * 64; i += 256) s_ew[i] = edge_w[i];
  for (int i = tid; i < 16 * 64; i += 256) s_w3[i] = mlp_w[256 * 64 + i];
  if (tid < 64) {
    s_w4[tid] = mlp_w[272 * 64 + tid];
    s_cw[tid] = coord_w[tid];
    s_eb[tid] = edge_b[tid];
  }
  const int base = blockIdx.x * 320;
  for (int t = tid; t < 320; t += 256) {
    s_src[t] = ei[base + t];
    s_dst[t] = ei[EE + base + t];
  }
  const float cb = COORD ? coord_b[0] : 0.f;
  __syncthreads();

  const int wb = w * 80;
  const int ebase = base + wb;
  const int pe = lane / 3;            // valid for lane < 24
  const int pc = lane - pe * 3;

  float p1n[8], p2n[8], p1c[8], p2c[8];
  float ean0, ean1, pdn = 0.f, psn = 0.f;

  // ---- prefetch issue for group g -> registers ----
  auto issue = [&](int g) {
    const int g8 = wb + g * 8;
#pragma unroll
    for (int e = 0; e < 8; ++e) {
      const int dn = s_dst[g8 + e];
      const int sn = s_src[g8 + e];
      p1n[e] = P1[dn * 64 + lane];
      p2n[e] = P2[sn * 64 + lane];
    }
    if (lane < 24) {
      const int dn = s_dst[g8 + pe];
      const int sn = s_src[g8 + pe];
      pdn = pos[dn * 3 + pc];
      psn = pos[sn * 3 + pc];
    }
    const int eb = ebase + g * 8;
    ean0 = eattr[eb * DD + lane];        // edge lane>>4,     k = lane&15
    ean1 = eattr[eb * DD + 64 + lane];   // edge 4+(lane>>4), k = lane&15
  };
  // ---- commit prefetched regs -> LDS buffer nb ----
  auto commit = [&](int nb) {
    if (lane < 24) s_diff[w][nb][lane] = pdn - psn;
    const int k0 = lane & 15, e0 = lane >> 4;
    s_eaT[w][nb][k0 * 8 + e0] = ean0;
    s_eaT[w][nb][k0 * 8 + 4 + e0] = ean1;
  };

  issue(0);
  commit(0);

  for (int g = 0; g < 10; ++g) {
    const int buf = g & 1;
#pragma unroll
    for (int e = 0; e < 8; ++e) { p1c[e] = p1n[e]; p2c[e] = p2n[e]; }
    if (g < 9) issue(g + 1);

    // radial from staged diffs
    float rad[8];
#pragma unroll
    for (int e = 0; e < 8; ++e) {
      const float r0 = s_diff[w][buf][e * 3 + 0];
      const float r1 = s_diff[w][buf][e * 3 + 1];
      const float r2 = s_diff[w][buf][e * 3 + 2];
      rad[e] = fmaf(r0, r0, fmaf(r1, r1, r2 * r2));
    }
    const float w4l = s_w4[lane];
    float acc[8];
#pragma unroll
    for (int e = 0; e < 8; ++e) acc[e] = p1c[e] + p2c[e] + rad[e] * w4l;
#pragma unroll
    for (int k = 0; k < 16; ++k) {
      const float4 a0 = *(const float4*)&s_eaT[w][buf][k * 8];
      const float4 a1 = *(const float4*)&s_eaT[w][buf][k * 8 + 4];
      const float wv = s_w3[k * 64 + lane];
      acc[0] = fmaf(a0.x, wv, acc[0]);
      acc[1] = fmaf(a0.y, wv, acc[1]);
      acc[2] = fmaf(a0.z, wv, acc[2]);
      acc[3] = fmaf(a0.w, wv, acc[3]);
      acc[4] = fmaf(a1.x, wv, acc[4]);
      acc[5] = fmaf(a1.y, wv, acc[5]);
      acc[6] = fmaf(a1.z, wv, acc[6]);
      acc[7] = fmaf(a1.w, wv, acc[7]);
    }
#pragma unroll
    for (int e = 0; e < 8; ++e) acc[e] = silu_f(acc[e]);
    *(float4*)&s_hT[w][lane * 8]     = make_float4(acc[0], acc[1], acc[2], acc[3]);
    *(float4*)&s_hT[w][lane * 8 + 4] = make_float4(acc[4], acc[5], acc[6], acc[7]);

    const float ebl = s_eb[lane];
    float o[8];
#pragma unroll
    for (int e = 0; e < 8; ++e) o[e] = ebl;
#pragma unroll 16
    for (int k = 0; k < 64; ++k) {
      const float wv = s_ew[k * 64 + lane];
      const float4 h0 = *(const float4*)&s_hT[w][k * 8];
      const float4 h1 = *(const float4*)&s_hT[w][k * 8 + 4];
      o[0] = fmaf(h0.x, wv, o[0]);
      o[1] = fmaf(h0.y, wv, o[1]);
      o[2] = fmaf(h0.z, wv, o[2]);
      o[3] = fmaf(h0.w, wv, o[3]);
      o[4] = fmaf(h1.x, wv, o[4]);
      o[5] = fmaf(h1.y, wv, o[5]);
      o[6] = fmaf(h1.z, wv, o[6]);
      o[7] = fmaf(h1.w, wv, o[7]);
    }
#pragma unroll
    for (int e = 0; e < 8; ++e) o[e] = silu_f(o[e]);

    if (g < 9) commit(buf ^ 1);   // vmcnt for prefetched loads fully hidden by compute

#pragma unroll
    for (int e = 0; e < 8; ++e) {
      const int dv = s_dst[wb + g * 8 + e];
      atomicAdd(&e_agg[dv * 64 + lane], o[e]);
    }
    if (COORD) {
#pragma unroll
      for (int e = 0; e < 8; ++e) {
        float vv = o[e] * s_cw[lane];
#pragma unroll
        for (int off = 32; off > 0; off >>= 1) vv += __shfl_xor(vv, off, 64);
        const float s = silu_f(vv + cb);
        const int dv = s_dst[wb + g * 8 + e];
        if (lane < 3) atomicAdd(&cu[dv * 3 + lane], s_diff[w][buf][e * 3 + lane] * s);
        if (lane == 3) atomicAdd(&deg[dv], 1.f);
      }
    }
  }
}

// ---------------- K3: node MLP (+ pos update on layer 0) ----------------
template <bool L0>
__global__ __launch_bounds__(256) void k_node(
    const float* __restrict__ x_in, const float* __restrict__ e_agg,
    const float* __restrict__ nw1, const float* __restrict__ nb1,
    const float* __restrict__ nw2, const float* __restrict__ nb2,
    const float* __restrict__ pos_in, const float* __restrict__ cu,
    const float* __restrict__ deg,
    float* __restrict__ x_out, float* __restrict__ pos_out) {
  __shared__ __align__(16) float xT[4][192 * 12];
  const int w = threadIdx.x >> 6, lane = threadIdx.x & 63;
  float* xt = xT[w];
  const int nb = (blockIdx.x * 4 + w) * 8;
#pragma unroll
  for (int e = 0; e < 8; ++e) {
    const int n = nb + e;
    const bool v = n < NN;
    xt[lane * 12 + e]         = v ? x_in[n * HIDC + lane] : 0.f;
    xt[(64 + lane) * 12 + e]  = v ? x_in[n * HIDC + 64 + lane] : 0.f;
    xt[(128 + lane) * 12 + e] = v ? e_agg[n * 64 + lane] : 0.f;
  }
  __syncthreads();
  float a[8];
#pragma unroll
  for (int e = 0; e < 8; ++e) a[e] = nb1[lane];
#pragma unroll 2
  for (int k = 0; k < 192; ++k) {
    const float wv = nw1[k * 64 + lane];
    float xk[8];
    *(float4*)&xk[0] = *(const float4*)&xt[k * 12];
    *(float4*)&xk[4] = *(const float4*)&xt[k * 12 + 4];
#pragma unroll
    for (int e = 0; e < 8; ++e) a[e] = fmaf(xk[e], wv, a[e]);
  }
#pragma unroll
  for (int e = 0; e < 8; ++e) a[e] = silu_f(a[e]);
  *(float4*)&xt[lane * 12]     = make_float4(a[0], a[1], a[2], a[3]);
  *(float4*)&xt[lane * 12 + 4] = make_float4(a[4], a[5], a[6], a[7]);
  float olo[8], ohi[8];
#pragma unroll
  for (int e = 0; e < 8; ++e) { olo[e] = nb2[lane]; ohi[e] = nb2[64 + lane]; }
#pragma unroll 2
  for (int k = 0; k < 64; ++k) {
    const float wl = nw2[k * HIDC + lane];
    const float wh = nw2[k * HIDC + 64 + lane];
    float hk[8];
    *(float4*)&hk[0] = *(const float4*)&xt[k * 12];
    *(float4*)&hk[4] = *(const float4*)&xt[k * 12 + 4];
#pragma unroll
    for (int e = 0; e < 8; ++e) {
      olo[e] = fmaf(hk[e], wl, olo[e]);
      ohi[e] = fmaf(hk[e], wh, ohi[e]);
    }
  }
#pragma unroll
  for (int e = 0; e < 8; ++e) {
    const int n = nb + e;
    if (n < NN) {
      x_out[n * HIDC + lane]      = olo[e];
      x_out[n * HIDC + 64 + lane] = ohi[e];
    }
  }
  if (L0) {
#pragma unroll
    for (int e = 0; e < 8; ++e) {
      const int n = nb + e;
      if (n < NN && lane < 3) {
        const float dg = fmaxf(deg[n], 1.f);
        pos_out[n * 3 + lane] = pos_in[n * 3 + lane] + cu[n * 3 + lane] / dg;
      }
    }
  }
}

// ---------------- K4: graph mean-pool partials (batch is sorted) ----------------
__global__ __launch_bounds__(128) void k_pool(
    const float* __restrict__ x, const int* __restrict__ batch,
    float* __restrict__ g_sum, float* __restrict__ g_cnt) {
  const int j = threadIdx.x;
  const int n0 = blockIdx.x * 256;
  const int n1 = min(n0 + 256, NN);
  int cur = batch[n0];
  float acc = 0.f, cnt = 0.f;
  for (int n = n0; n < n1; ++n) {
    const int b = batch[n];
    if (b != cur) {
      atomicAdd(&g_sum[cur * HIDC + j], acc);
      if (j == 0) atomicAdd(&g_cnt[cur], cnt);
      acc = 0.f; cnt = 0.f; cur = b;
    }
    acc += x[n * HIDC + j];
    cnt += 1.f;
  }
  atomicAdd(&g_sum[cur * HIDC + j], acc);
  if (j == 0) atomicAdd(&g_cnt[cur], cnt);
}

// ---------------- K5: relu(mean) -> relu(@w1+b1) -> @w2+b2 ----------------
__global__ __launch_bounds__(128) void k_final(
    const float* __restrict__ g_sum, const float* __restrict__ g_cnt,
    const float* __restrict__ w1, const float* __restrict__ b1,
    const float* __restrict__ w2, const float* __restrict__ b2,
    float* __restrict__ out) {
  __shared__ float sg[128];
  __shared__ float sh[128];
  const int g = blockIdx.x, j = threadIdx.x;
  const float c = fmaxf(g_cnt[g], 1.f);
  sg[j] = fmaxf(g_sum[g * HIDC + j] / c, 0.f);
  __syncthreads();
  float a = b1[j];
  for (int k = 0; k < 128; ++k) a += sg[k] * w1[k * 128 + j];
  sh[j] = fmaxf(a, 0.f);
  __syncthreads();
  if (j < OUTC) {
    float o = b2[j];
    for (int k = 0; k < 128; ++k) o += sh[k] * w2[k * OUTC + j];
    out[g * OUTC + j] = o;
  }
}

extern "C" void kernel_launch(void* const* d_in, const int* in_sizes, int n_in,
                              void* d_out, int out_size, void* d_ws, size_t ws_size,
                              hipStream_t stream) {
  const float* x     = (const float*)d_in[0];
  const float* pos   = (const float*)d_in[1];
  const float* eattr = (const float*)d_in[2];
  const int*   ei    = (const int*)d_in[3];
  const int*   batch = (const int*)d_in[4];
  const float* mlp_w[2]   = {(const float*)d_in[5],  (const float*)d_in[14]};
  const float* edge_w[2]  = {(const float*)d_in[6],  (const float*)d_in[15]};
  const float* edge_b[2]  = {(const float*)d_in[7],  (const float*)d_in[16]};
  const float* coord_w[2] = {(const float*)d_in[8],  (const float*)d_in[17]};
  const float* coord_b[2] = {(const float*)d_in[9],  (const float*)d_in[18]};
  const float* nw1[2]     = {(const float*)d_in[10], (const float*)d_in[19]};
  const float* nb1[2]     = {(const float*)d_in[11], (const float*)d_in[20]};
  const float* nw2[2]     = {(const float*)d_in[12], (const float*)d_in[21]};
  const float* nb2[2]     = {(const float*)d_in[13], (const float*)d_in[22]};
  const float* ow1 = (const float*)d_in[23];
  const float* ob1 = (const float*)d_in[24];
  const float* ow2 = (const float*)d_in[25];
  const float* ob2 = (const float*)d_in[26];
  float* out = (float*)d_out;

  char* p = (char*)d_ws;
  auto alloc = [&](size_t bytes) {
    float* r = (float*)p;
    p += (bytes + 255) & ~(size_t)255;
    return r;
  };
  float* P1    = alloc((size_t)NN * 64 * 4);
  float* P2    = alloc((size_t)NN * 64 * 4);
  float* e_agg = alloc((size_t)NN * 64 * 4);
  float* cu    = alloc((size_t)NN * 3 * 4);
  float* deg   = alloc((size_t)NN * 4);
  float* x1    = alloc((size_t)NN * HIDC * 4);
  float* pos1  = alloc((size_t)NN * 3 * 4);
  float* g_sum = alloc((size_t)GG * HIDC * 4);
  float* g_cnt = alloc((size_t)GG * 4);
  float* x2    = P1;  // alias: P1/P2 dead after layer-1 k_edge

  const int nodeBlocks = (NN + 31) / 32;
  const int edgeBlocks = 1250;  // 1250 x 4 waves x 80 edges = 400000

  hipMemsetAsync(e_agg, 0, (size_t)NN * 64 * 4, stream);
  hipMemsetAsync(cu,    0, (size_t)NN * 3 * 4, stream);
  hipMemsetAsync(deg,   0, (size_t)NN * 4, stream);
  hipMemsetAsync(g_sum, 0, (size_t)GG * HIDC * 4, stream);
  hipMemsetAsync(g_cnt, 0, (size_t)GG * 4, stream);

  // ---- layer 0 ----
  k_precompute<<<nodeBlocks, 256, 0, stream>>>(x, mlp_w[0], P1, P2);
  k_edge<true><<<edgeBlocks, 256, 0, stream>>>(P1, P2, pos, eattr, ei, mlp_w[0],
      edge_w[0], edge_b[0], coord_w[0], coord_b[0], e_agg, cu, deg);
  k_node<true><<<nodeBlocks, 256, 0, stream>>>(x, e_agg, nw1[0], nb1[0],
      nw2[0], nb2[0], pos, cu, deg, x1, pos1);

  // ---- layer 1 (output pos unused -> skip coord path) ----
  hipMemsetAsync(e_agg, 0, (size_t)NN * 64 * 4, stream);
  k_precompute<<<nodeBlocks, 256, 0, stream>>>(x1, mlp_w[1], P1, P2);
  k_edge<false><<<edgeBlocks, 256, 0, stream>>>(P1, P2, pos1, eattr, ei, mlp_w[1],
      edge_w[1], edge_b[1], coord_w[1], coord_b[1], e_agg, cu, deg);
  k_node<false><<<nodeBlocks, 256, 0, stream>>>(x1, e_agg, nw1[1], nb1[1],
      nw2[1], nb2[1], pos1, cu, deg, x2, pos1);

  // ---- pooling + head ----
  k_pool<<<(NN + 255) / 256, 128, 0, stream>>>(x2, batch, g_sum, g_cnt);
  k_final<<<GG, 128, 0, stream>>>(g_sum, g_cnt, ow1, ob1, ow2, ob2, out);
}